// Round 1
// baseline (1000.237 us; speedup 1.0000x reference)
//
#include <hip/hip_runtime.h>
#include <cstdint>

#define DEV __device__ __forceinline__

constexpr int Bz = 8, Tz = 4096, Cz = 1024;
constexpr int Mz = Bz * Tz;           // 32768 rows
constexpr int Sz = 32, Lz = 128;      // scan: 32 chunks x 128 steps = T

using bf16x8  = __attribute__((ext_vector_type(8))) __bf16;
using floatx4 = __attribute__((ext_vector_type(4))) float;

DEV float bf2f(unsigned short u) { return __uint_as_float(((uint32_t)u) << 16); }
DEV unsigned short f2bf(float f) {            // round-to-nearest-even
    uint32_t u = __float_as_uint(f);
    u += 0x7fffu + ((u >> 16) & 1u);
    return (unsigned short)(u >> 16);
}

DEV void gl2lds16(const unsigned short* g, unsigned short* l) {
    __builtin_amdgcn_global_load_lds(
        (const __attribute__((address_space(1))) void*)g,
        (__attribute__((address_space(3))) void*)l, 16, 0, 0);
}

// ---------------- weight fp32 -> bf16 ----------------
__global__ __launch_bounds__(256) void f2b_k(const float* __restrict__ src,
                                             unsigned short* __restrict__ dst, int n4) {
    int i = blockIdx.x * 256 + threadIdx.x;
    if (i >= n4) return;
    float4 v = ((const float4*)src)[i];
    ushort4 o;
    o.x = f2bf(v.x); o.y = f2bf(v.y); o.z = f2bf(v.z); o.w = f2bf(v.w);
    ((ushort4*)dst)[i] = o;
}

// ---------------- time-mix: xk/xv/xr (bf16) ----------------
DEV ushort4 mix4(float4 m, float4 xc, float4 xp) {
    ushort4 o;
    o.x = f2bf(fmaf(m.x, xc.x - xp.x, xp.x));
    o.y = f2bf(fmaf(m.y, xc.y - xp.y, xp.y));
    o.z = f2bf(fmaf(m.z, xc.z - xp.z, xp.z));
    o.w = f2bf(fmaf(m.w, xc.w - xp.w, xp.w));
    return o;
}

__global__ __launch_bounds__(256) void mix_k(const float* __restrict__ x,
    const float* __restrict__ mk, const float* __restrict__ mv, const float* __restrict__ mr,
    unsigned short* __restrict__ xk, unsigned short* __restrict__ xv,
    unsigned short* __restrict__ xr) {
    int gid = blockIdx.x * 256 + threadIdx.x;       // float4 group; total Mz*Cz/4
    int m   = gid >> 8;                             // row = b*T + t   (Cz/4 = 256)
    int c4  = gid & 255;
    float4 xc = ((const float4*)x)[gid];
    float4 xp = make_float4(0.f, 0.f, 0.f, 0.f);
    if ((m & (Tz - 1)) != 0) xp = ((const float4*)x)[gid - 256];   // x[b, t-1]
    ((ushort4*)xk)[gid] = mix4(((const float4*)mk)[c4], xc, xp);
    ((ushort4*)xv)[gid] = mix4(((const float4*)mv)[c4], xc, xp);
    ((ushort4*)xr)[gid] = mix4(((const float4*)mr)[c4], xc, xp);
}

// ---------------- bf16 NT GEMM (m97 structure) ----------------
// C[m,n] = sum_k A[m,k] * Bw[n,k];  M=32768, N=1024, K=1024
// mode 0: fp32 store; mode 1: bf16 store; mode 2: sigmoid -> bf16 store
__global__ __launch_bounds__(256) void gemm_bt(const unsigned short* __restrict__ A,
                                               const unsigned short* __restrict__ Bw,
                                               void* __restrict__ Cout, int mode) {
    constexpr int Mt = 128, Nt = 128, Kt = 32, Kd = 1024, Nd = 1024;
    __shared__ unsigned short lA[Mt * Kt];
    __shared__ unsigned short lB[Nt * Kt];

    const int tid  = threadIdx.x;
    const int m0   = blockIdx.x * Mt;
    const int n0   = blockIdx.y * Nt;
    const int lane = tid & 63;
    const int wave = tid >> 6;
    const int wm   = (wave >> 1) * 64, wn = (wave & 1) * 64;
    const int l15  = lane & 15, kseg = lane >> 4;

    // staging: thread t loads 16B at row t>>2, k-col (t&3)*8; 2 insts cover 128 rows
    const unsigned short* ga0 = A  + (size_t)(m0 + (tid >> 2)) * Kd + (tid & 3) * 8;
    const unsigned short* gb0 = Bw + (size_t)(n0 + (tid >> 2)) * Kd + (tid & 3) * 8;
    unsigned short* la = lA + tid * 8;
    unsigned short* lb = lB + tid * 8;

    floatx4 acc[4][4];
#pragma unroll
    for (int mi = 0; mi < 4; mi++)
#pragma unroll
        for (int ni = 0; ni < 4; ni++) acc[mi][ni] = (floatx4){0.f, 0.f, 0.f, 0.f};

    for (int kt = 0; kt < Kd; kt += Kt) {
        gl2lds16(ga0 + kt, la);
        gl2lds16(ga0 + kt + (size_t)64 * Kd, la + 64 * Kt);
        gl2lds16(gb0 + kt, lb);
        gl2lds16(gb0 + kt + (size_t)64 * Kd, lb + 64 * Kt);
        __syncthreads();   // compiler emits s_waitcnt vmcnt(0) before s_barrier

        bf16x8 af[4], bfr[4];
#pragma unroll
        for (int i = 0; i < 4; i++) {
            af[i]  = *(const bf16x8*)(lA + (wm + i * 16 + l15) * Kt + kseg * 8);
            bfr[i] = *(const bf16x8*)(lB + (wn + i * 16 + l15) * Kt + kseg * 8);
        }
#pragma unroll
        for (int mi = 0; mi < 4; mi++)
#pragma unroll
            for (int ni = 0; ni < 4; ni++)
                acc[mi][ni] = __builtin_amdgcn_mfma_f32_16x16x32_bf16(
                    af[mi], bfr[ni], acc[mi][ni], 0, 0, 0);
        __syncthreads();
    }

    // epilogue: D col = lane&15, row = (lane>>4)*4 + reg   [m89 verified]
    const int cr = kseg * 4;
#pragma unroll
    for (int mi = 0; mi < 4; mi++) {
#pragma unroll
        for (int ni = 0; ni < 4; ni++) {
            size_t row = (size_t)(m0 + wm + mi * 16 + cr);
            size_t col = (size_t)(n0 + wn + ni * 16 + l15);
#pragma unroll
            for (int rg = 0; rg < 4; rg++) {
                float v = acc[mi][ni][rg];
                size_t idx = (row + rg) * Nd + col;
                if (mode == 0) {
                    ((float*)Cout)[idx] = v;
                } else if (mode == 1) {
                    ((unsigned short*)Cout)[idx] = f2bf(v);
                } else {
                    float sg = 1.0f / (1.0f + __expf(-v));
                    ((unsigned short*)Cout)[idx] = f2bf(sg);
                }
            }
        }
    }
}

// ---------------- WKV scan, 3-pass chunked linear recurrence ----------------
// unnormalized state: A_t = lam*A + e^k * v ; B_t = lam*B + e^k  (fp32-safe here)

__global__ __launch_bounds__(256) void wkv_pass1(const float* __restrict__ kf,
    const unsigned short* __restrict__ vb, const float* __restrict__ td,
    float* __restrict__ SA, float* __restrict__ SB) {
    int tid = blockIdx.x * 256 + threadIdx.x;   // B*S*C threads
    int c   = tid & (Cz - 1);
    int bs  = tid >> 10;                        // b*S + s
    int b   = bs >> 5, s = bs & (Sz - 1);
    float w   = -__expf(td[c]);
    float lam = __expf(w);
    size_t base = ((size_t)(b * Tz + s * Lz)) * Cz + c;
    float pa = 0.f, pb = 0.f;
#pragma unroll 4
    for (int i = 0; i < Lz; i++) {
        size_t idx = base + (size_t)i * Cz;
        float kk = kf[idx];
        float vv = bf2f(vb[idx]);
        float ek = __expf(kk);
        pa = fmaf(pa, lam, ek * vv);
        pb = fmaf(pb, lam, ek);
    }
    SA[tid] = pa;   // layout (b*S+s)*C + c == tid
    SB[tid] = pb;
}

__global__ __launch_bounds__(256) void wkv_pass2(const float* __restrict__ td,
                                                 float* __restrict__ SA,
                                                 float* __restrict__ SB) {
    int tid = blockIdx.x * 256 + threadIdx.x;   // B*C threads
    int c   = tid & (Cz - 1);
    int b   = tid >> 10;
    float w    = -__expf(td[c]);
    float lamL = __expf(w * (float)Lz);
    float A = 0.f, Bv = 0.f;
    for (int s = 0; s < Sz; s++) {
        size_t idx = ((size_t)(b * Sz + s)) * Cz + c;
        float ta = SA[idx], tb = SB[idx];
        SA[idx] = A; SB[idx] = Bv;              // exclusive prefix = chunk-start state
        A  = fmaf(A, lamL, ta);
        Bv = fmaf(Bv, lamL, tb);
    }
}

__global__ __launch_bounds__(256) void wkv_pass3(const float* __restrict__ kf,
    const unsigned short* __restrict__ vb, const unsigned short* __restrict__ rb,
    const float* __restrict__ td, const float* __restrict__ tf,
    const float* __restrict__ SA, const float* __restrict__ SB,
    unsigned short* __restrict__ ry) {
    int tid = blockIdx.x * 256 + threadIdx.x;
    int c   = tid & (Cz - 1);
    int bs  = tid >> 10;
    int b   = bs >> 5, s = bs & (Sz - 1);
    float w   = -__expf(td[c]);
    float lam = __expf(w);
    float eu  = __expf(tf[c]);
    float A = SA[tid], Bv = SB[tid];
    size_t base = ((size_t)(b * Tz + s * Lz)) * Cz + c;
#pragma unroll 2
    for (int i = 0; i < Lz; i++) {
        size_t idx = base + (size_t)i * Cz;
        float kk = kf[idx];
        float vv = bf2f(vb[idx]);
        float rr = bf2f(rb[idx]);
        float ek = __expf(kk);
        float ekv = ek * vv;
        float num = fmaf(A, eu, ekv);
        float den = fmaf(Bv, eu, ek);           // >= e^k > 0; ref's 1e-6 is <=1e-6 rel
        float y = num * __builtin_amdgcn_rcpf(den);
        ry[idx] = f2bf(rr * y);
        A  = fmaf(A, lam, ekv);
        Bv = fmaf(Bv, lam, ek);
    }
}

// ---------------- launcher ----------------
extern "C" void kernel_launch(void* const* d_in, const int* in_sizes, int n_in,
                              void* d_out, int out_size, void* d_ws, size_t ws_size,
                              hipStream_t stream) {
    const float* x  = (const float*)d_in[0];
    const float* td = (const float*)d_in[1];
    const float* tf = (const float*)d_in[2];
    const float* mk = (const float*)d_in[3];
    const float* mv = (const float*)d_in[4];
    const float* mr = (const float*)d_in[5];
    const float* Wk = (const float*)d_in[6];
    const float* Wv = (const float*)d_in[7];
    const float* Wr = (const float*)d_in[8];
    const float* Wo = (const float*)d_in[9];

    constexpr size_t SZ_BF = (size_t)Mz * Cz * 2;       // 64 MB
    constexpr size_t SZ_F  = (size_t)Mz * Cz * 4;       // 128 MB
    constexpr size_t SZ_W  = (size_t)Cz * Cz * 2;       // 2 MB
    constexpr size_t SZ_S  = (size_t)Bz * Sz * Cz * 4;  // 1 MB

    char* ws = (char*)d_ws;
    unsigned short* xk  = (unsigned short*)(ws);
    unsigned short* xv  = (unsigned short*)(ws + SZ_BF);
    unsigned short* xr  = (unsigned short*)(ws + 2 * SZ_BF);
    float*          kf  = (float*)         (ws + 3 * SZ_BF);
    unsigned short* vb  = (unsigned short*)(ws + 3 * SZ_BF + SZ_F);
    unsigned short* rb  = (unsigned short*)(ws + 4 * SZ_BF + SZ_F);
    unsigned short* wkb = (unsigned short*)(ws + 5 * SZ_BF + SZ_F);
    unsigned short* wvb = (unsigned short*)(ws + 5 * SZ_BF + SZ_F + SZ_W);
    unsigned short* wrb = (unsigned short*)(ws + 5 * SZ_BF + SZ_F + 2 * SZ_W);
    unsigned short* wob = (unsigned short*)(ws + 5 * SZ_BF + SZ_F + 3 * SZ_W);
    float*          SA  = (float*)         (ws + 5 * SZ_BF + SZ_F + 4 * SZ_W);
    float*          SB  = (float*)         (ws + 5 * SZ_BF + SZ_F + 4 * SZ_W + SZ_S);
    unsigned short* ry  = xk;   // xk is dead after the k-GEMM; reuse for r*y

    const int wn4 = Cz * Cz / 4;
    f2b_k<<<dim3((wn4 + 255) / 256), dim3(256), 0, stream>>>(Wk, wkb, wn4);
    f2b_k<<<dim3((wn4 + 255) / 256), dim3(256), 0, stream>>>(Wv, wvb, wn4);
    f2b_k<<<dim3((wn4 + 255) / 256), dim3(256), 0, stream>>>(Wr, wrb, wn4);
    f2b_k<<<dim3((wn4 + 255) / 256), dim3(256), 0, stream>>>(Wo, wob, wn4);

    mix_k<<<dim3(Mz * Cz / 4 / 256), dim3(256), 0, stream>>>(x, mk, mv, mr, xk, xv, xr);

    dim3 ggrid(Mz / 128, Cz / 128);
    gemm_bt<<<ggrid, dim3(256), 0, stream>>>(xk, wkb, (void*)kf, 0);   // k fp32
    gemm_bt<<<ggrid, dim3(256), 0, stream>>>(xv, wvb, (void*)vb, 1);   // v bf16
    gemm_bt<<<ggrid, dim3(256), 0, stream>>>(xr, wrb, (void*)rb, 2);   // r = sigmoid, bf16

    wkv_pass1<<<dim3(Bz * Sz * Cz / 256), dim3(256), 0, stream>>>(kf, vb, td, SA, SB);
    wkv_pass2<<<dim3(Bz * Cz / 256), dim3(256), 0, stream>>>(td, SA, SB);
    wkv_pass3<<<dim3(Bz * Sz * Cz / 256), dim3(256), 0, stream>>>(kf, vb, rb, td, tf,
                                                                  SA, SB, ry);

    gemm_bt<<<ggrid, dim3(256), 0, stream>>>(ry, wob, d_out, 0);       // out fp32
}

// Round 2
// 878.942 us; speedup vs baseline: 1.1380x; 1.1380x over previous
//
#include <hip/hip_runtime.h>
#include <cstdint>

#define DEV __device__ __forceinline__

constexpr int Bz = 8, Tz = 4096, Cz = 1024;
constexpr int Mz = Bz * Tz;           // 32768 rows
constexpr int Sz = 32, Lz = 128;      // scan: 32 chunks x 128 steps = T

using bf16x8  = __attribute__((ext_vector_type(8))) __bf16;
using floatx4 = __attribute__((ext_vector_type(4))) float;

DEV float bf2f(unsigned short u) { return __uint_as_float(((uint32_t)u) << 16); }
DEV unsigned short f2bf(float f) {            // round-to-nearest-even
    uint32_t u = __float_as_uint(f);
    u += 0x7fffu + ((u >> 16) & 1u);
    return (unsigned short)(u >> 16);
}
DEV unsigned short f2h(float f) {
    _Float16 h = (_Float16)f;
    unsigned short u;
    __builtin_memcpy(&u, &h, 2);
    return u;
}
DEV float h2f(unsigned short u) {
    _Float16 h;
    __builtin_memcpy(&h, &u, 2);
    return (float)h;
}

DEV void gl2lds16(const unsigned short* g, unsigned short* l) {
    __builtin_amdgcn_global_load_lds(
        (const __attribute__((address_space(1))) void*)g,
        (__attribute__((address_space(3))) void*)l, 16, 0, 0);
}

// ---------------- weight fp32 -> bf16 (all 4 weights, one dispatch) ----------------
__global__ __launch_bounds__(256) void f2b_k(const float* __restrict__ w0,
                                             const float* __restrict__ w1,
                                             const float* __restrict__ w2,
                                             const float* __restrict__ w3,
                                             unsigned short* __restrict__ dst) {
    int which = blockIdx.y;
    const float* src = which == 0 ? w0 : which == 1 ? w1 : which == 2 ? w2 : w3;
    int i = blockIdx.x * 256 + threadIdx.x;          // float4 idx within one weight
    float4 v = ((const float4*)src)[i];
    ushort4 o;
    o.x = f2bf(v.x); o.y = f2bf(v.y); o.z = f2bf(v.z); o.w = f2bf(v.w);
    ((ushort4*)(dst + (size_t)which * Cz * Cz))[i] = o;
}

// ---------------- time-mix: xk/xv/xr (bf16) ----------------
DEV ushort4 mix4(float4 m, float4 xc, float4 xp) {
    ushort4 o;
    o.x = f2bf(fmaf(m.x, xc.x - xp.x, xp.x));
    o.y = f2bf(fmaf(m.y, xc.y - xp.y, xp.y));
    o.z = f2bf(fmaf(m.z, xc.z - xp.z, xp.z));
    o.w = f2bf(fmaf(m.w, xc.w - xp.w, xp.w));
    return o;
}

__global__ __launch_bounds__(256) void mix_k(const float* __restrict__ x,
    const float* __restrict__ mk, const float* __restrict__ mv, const float* __restrict__ mr,
    unsigned short* __restrict__ xk, unsigned short* __restrict__ xv,
    unsigned short* __restrict__ xr) {
    int gid = blockIdx.x * 256 + threadIdx.x;       // float4 group; total Mz*Cz/4
    int m   = gid >> 8;                             // row = b*T + t   (Cz/4 = 256)
    int c4  = gid & 255;
    float4 xc = ((const float4*)x)[gid];
    float4 xp = make_float4(0.f, 0.f, 0.f, 0.f);
    if ((m & (Tz - 1)) != 0) xp = ((const float4*)x)[gid - 256];   // x[b, t-1]
    ((ushort4*)xk)[gid] = mix4(((const float4*)mk)[c4], xc, xp);
    ((ushort4*)xv)[gid] = mix4(((const float4*)mv)[c4], xc, xp);
    ((ushort4*)xr)[gid] = mix4(((const float4*)mr)[c4], xc, xp);
}

// ---------------- bf16 NT GEMM, BK=64, XCD-swizzled ----------------
// C[m,n] = sum_k A[m,k] * Bw[n,k];  M=32768, N=K=1024
// grid (8, 256, nz); z selects A/out/mode.  modes packed 4b each:
//   0: fp32 store; 1: bf16; 2: sigmoid->bf16; 3: f16
__global__ __launch_bounds__(256) void gemm_bt(
        const unsigned short* __restrict__ A0, const unsigned short* __restrict__ A1,
        const unsigned short* __restrict__ A2,
        const unsigned short* __restrict__ Bw0, const unsigned short* __restrict__ Bw1,
        const unsigned short* __restrict__ Bw2,
        void* __restrict__ O0, void* __restrict__ O1, void* __restrict__ O2,
        int modes) {
    constexpr int Kd = 1024, Nd = 1024;
    __shared__ unsigned short lA[2][128 * 32];   // two 32-wide K halves, 16 KB
    __shared__ unsigned short lB[2][128 * 32];   // 16 KB

    const int z = blockIdx.z;
    const unsigned short* A  = z == 0 ? A0  : z == 1 ? A1  : A2;
    const unsigned short* Bw = z == 0 ? Bw0 : z == 1 ? Bw1 : Bw2;
    void* Cout = z == 0 ? O0 : z == 1 ? O1 : O2;
    const int mode = (modes >> (z * 4)) & 15;

    // XCD swizzle: assume linear-dispatch round-robin over 8 XCDs.
    // Put the 8 n-blocks that share one A row-slice adjacent on ONE xcd.
    const int L    = blockIdx.y * 8 + blockIdx.x;   // dispatch-linear id, 0..2047
    const int xcd  = L & 7, slot = L >> 3;
    const int mb   = xcd * 32 + (slot >> 3);        // 0..255
    const int nb   = slot & 7;                      // 0..7
    const int m0   = mb * 128, n0 = nb * 128;

    const int tid  = threadIdx.x;
    const int lane = tid & 63;
    const int wave = tid >> 6;
    const int wm   = (wave >> 1) * 64, wn = (wave & 1) * 64;
    const int l15  = lane & 15, kseg = lane >> 4;

    // staging: per 128x32 half, 2 insts; thread t -> row t>>2 (+64), col (t&3)*8
    const unsigned short* gA = A  + (size_t)(m0 + (tid >> 2)) * Kd + (tid & 3) * 8;
    const unsigned short* gB = Bw + (size_t)(n0 + (tid >> 2)) * Kd + (tid & 3) * 8;

    floatx4 acc[4][4];
#pragma unroll
    for (int mi = 0; mi < 4; mi++)
#pragma unroll
        for (int ni = 0; ni < 4; ni++) acc[mi][ni] = (floatx4){0.f, 0.f, 0.f, 0.f};

    for (int kt = 0; kt < Kd; kt += 64) {
#pragma unroll
        for (int h = 0; h < 2; h++) {
            gl2lds16(gA + kt + h * 32,                   &lA[h][tid * 8]);
            gl2lds16(gA + kt + h * 32 + (size_t)64 * Kd, &lA[h][2048 + tid * 8]);
            gl2lds16(gB + kt + h * 32,                   &lB[h][tid * 8]);
            gl2lds16(gB + kt + h * 32 + (size_t)64 * Kd, &lB[h][2048 + tid * 8]);
        }
        __syncthreads();

#pragma unroll
        for (int h = 0; h < 2; h++) {
            bf16x8 af[4], bfr[4];
#pragma unroll
            for (int i = 0; i < 4; i++) {
                af[i]  = *(const bf16x8*)&lA[h][(wm + i * 16 + l15) * 32 + kseg * 8];
                bfr[i] = *(const bf16x8*)&lB[h][(wn + i * 16 + l15) * 32 + kseg * 8];
            }
#pragma unroll
            for (int mi = 0; mi < 4; mi++)
#pragma unroll
                for (int ni = 0; ni < 4; ni++)
                    acc[mi][ni] = __builtin_amdgcn_mfma_f32_16x16x32_bf16(
                        af[mi], bfr[ni], acc[mi][ni], 0, 0, 0);
        }
        __syncthreads();
    }

    // epilogue: D col = lane&15, row = (lane>>4)*4 + reg   [m89 verified]
    const int cr = kseg * 4;
#pragma unroll
    for (int mi = 0; mi < 4; mi++) {
#pragma unroll
        for (int ni = 0; ni < 4; ni++) {
            size_t row = (size_t)(m0 + wm + mi * 16 + cr);
            size_t col = (size_t)(n0 + wn + ni * 16 + l15);
#pragma unroll
            for (int rg = 0; rg < 4; rg++) {
                float v = acc[mi][ni][rg];
                size_t idx = (row + rg) * Nd + col;
                if (mode == 0) {
                    ((float*)Cout)[idx] = v;
                } else if (mode == 1) {
                    ((unsigned short*)Cout)[idx] = f2bf(v);
                } else if (mode == 2) {
                    float sg = 1.0f / (1.0f + __expf(-v));
                    ((unsigned short*)Cout)[idx] = f2bf(sg);
                } else {
                    ((unsigned short*)Cout)[idx] = f2h(v);
                }
            }
        }
    }
}

// ---------------- WKV scan, 3-pass chunked linear recurrence ----------------
// unnormalized state: A_t = lam*A + e^k * v ; B_t = lam*B + e^k  (fp32-safe:
// |k|<~6, 1/(1-lam)<=400 -> state in [e^-6, ~1e5])
// 2 channels per thread; k stored f16, v/r bf16.

__global__ __launch_bounds__(256) void wkv_pass1(const unsigned short* __restrict__ kh,
    const unsigned short* __restrict__ vb, const float* __restrict__ td,
    float2* __restrict__ SA, float2* __restrict__ SB) {
    int tid = blockIdx.x * 256 + threadIdx.x;   // B*S*C/2 threads
    int c2  = tid & 511;
    int bs  = tid >> 9;                         // b*S + s
    int b   = bs >> 5, s = bs & (Sz - 1);
    int c   = c2 * 2;
    float lam0 = __expf(-__expf(td[c]));
    float lam1 = __expf(-__expf(td[c + 1]));
    size_t base = (((size_t)(b * Tz + s * Lz)) * Cz + c) >> 1;   // ushort2 index
    float pa0 = 0.f, pb0 = 0.f, pa1 = 0.f, pb1 = 0.f;
#pragma unroll 4
    for (int i = 0; i < Lz; i++) {
        size_t idx = base + (size_t)i * (Cz / 2);
        ushort2 kk = ((const ushort2*)kh)[idx];
        ushort2 vv = ((const ushort2*)vb)[idx];
        float e0 = __expf(h2f(kk.x)), e1 = __expf(h2f(kk.y));
        pa0 = fmaf(pa0, lam0, e0 * bf2f(vv.x));
        pb0 = fmaf(pb0, lam0, e0);
        pa1 = fmaf(pa1, lam1, e1 * bf2f(vv.y));
        pb1 = fmaf(pb1, lam1, e1);
    }
    SA[tid] = make_float2(pa0, pa1);   // layout (b*S+s)*512 + c2
    SB[tid] = make_float2(pb0, pb1);
}

__global__ __launch_bounds__(256) void wkv_pass2(const float* __restrict__ td,
                                                 float2* __restrict__ SA,
                                                 float2* __restrict__ SB) {
    int tid = blockIdx.x * 256 + threadIdx.x;   // B*C/2 threads
    int c2  = tid & 511;
    int b   = tid >> 9;
    int c   = c2 * 2;
    float lamL0 = __expf(-__expf(td[c]) * (float)Lz);
    float lamL1 = __expf(-__expf(td[c + 1]) * (float)Lz);
    float A0 = 0.f, B0 = 0.f, A1 = 0.f, B1 = 0.f;
    for (int s = 0; s < Sz; s++) {
        size_t idx = ((size_t)(b * Sz + s)) * 512 + c2;
        float2 ta = SA[idx], tb = SB[idx];
        SA[idx] = make_float2(A0, A1);          // exclusive prefix = chunk-start state
        SB[idx] = make_float2(B0, B1);
        A0 = fmaf(A0, lamL0, ta.x);  B0 = fmaf(B0, lamL0, tb.x);
        A1 = fmaf(A1, lamL1, ta.y);  B1 = fmaf(B1, lamL1, tb.y);
    }
}

__global__ __launch_bounds__(256) void wkv_pass3(const unsigned short* __restrict__ kh,
    const unsigned short* __restrict__ vb, const unsigned short* __restrict__ rb,
    const float* __restrict__ td, const float* __restrict__ tf,
    const float2* __restrict__ SA, const float2* __restrict__ SB,
    unsigned short* __restrict__ ry) {
    int tid = blockIdx.x * 256 + threadIdx.x;
    int c2  = tid & 511;
    int bs  = tid >> 9;
    int b   = bs >> 5, s = bs & (Sz - 1);
    int c   = c2 * 2;
    float lam0 = __expf(-__expf(td[c]));
    float lam1 = __expf(-__expf(td[c + 1]));
    float eu0  = __expf(tf[c]);
    float eu1  = __expf(tf[c + 1]);
    float2 fa = SA[tid], fb = SB[tid];
    float A0 = fa.x, A1 = fa.y, B0 = fb.x, B1 = fb.y;
    size_t base = (((size_t)(b * Tz + s * Lz)) * Cz + c) >> 1;
#pragma unroll 2
    for (int i = 0; i < Lz; i++) {
        size_t idx = base + (size_t)i * (Cz / 2);
        ushort2 kk = ((const ushort2*)kh)[idx];
        ushort2 vv = ((const ushort2*)vb)[idx];
        ushort2 rr = ((const ushort2*)rb)[idx];
        float e0 = __expf(h2f(kk.x)), e1 = __expf(h2f(kk.y));
        float ev0 = e0 * bf2f(vv.x), ev1 = e1 * bf2f(vv.y);
        float y0 = fmaf(A0, eu0, ev0) * __builtin_amdgcn_rcpf(fmaf(B0, eu0, e0));
        float y1 = fmaf(A1, eu1, ev1) * __builtin_amdgcn_rcpf(fmaf(B1, eu1, e1));
        ushort2 o;
        o.x = f2bf(bf2f(rr.x) * y0);
        o.y = f2bf(bf2f(rr.y) * y1);
        ((ushort2*)ry)[idx] = o;
        A0 = fmaf(A0, lam0, ev0);  B0 = fmaf(B0, lam0, e0);
        A1 = fmaf(A1, lam1, ev1);  B1 = fmaf(B1, lam1, e1);
    }
}

// ---------------- launcher ----------------
extern "C" void kernel_launch(void* const* d_in, const int* in_sizes, int n_in,
                              void* d_out, int out_size, void* d_ws, size_t ws_size,
                              hipStream_t stream) {
    const float* x  = (const float*)d_in[0];
    const float* td = (const float*)d_in[1];
    const float* tf = (const float*)d_in[2];
    const float* mk = (const float*)d_in[3];
    const float* mv = (const float*)d_in[4];
    const float* mr = (const float*)d_in[5];
    const float* Wk = (const float*)d_in[6];
    const float* Wv = (const float*)d_in[7];
    const float* Wr = (const float*)d_in[8];
    const float* Wo = (const float*)d_in[9];

    constexpr size_t SZ_BF = (size_t)Mz * Cz * 2;       // 64 MB
    constexpr size_t SZ_W  = (size_t)Cz * Cz * 2;       // 2 MB
    constexpr size_t SZ_S  = (size_t)Bz * Sz * Cz * 4;  // 1 MB

    char* ws = (char*)d_ws;
    unsigned short* xk  = (unsigned short*)(ws);
    unsigned short* xv  = (unsigned short*)(ws + SZ_BF);
    unsigned short* xr  = (unsigned short*)(ws + 2 * SZ_BF);
    unsigned short* kf  = (unsigned short*)(ws + 3 * SZ_BF);   // f16
    unsigned short* vb  = (unsigned short*)(ws + 4 * SZ_BF);   // bf16
    unsigned short* rb  = (unsigned short*)(ws + 5 * SZ_BF);   // bf16
    unsigned short* wts = (unsigned short*)(ws + 6 * SZ_BF);   // wk|wv|wr|wo
    float2*         SA  = (float2*)        (ws + 6 * SZ_BF + 4 * SZ_W);
    float2*         SB  = (float2*)        (ws + 6 * SZ_BF + 4 * SZ_W + SZ_S);
    unsigned short* wkb = wts;
    unsigned short* wvb = wts + (size_t)Cz * Cz;
    unsigned short* wrb = wts + (size_t)2 * Cz * Cz;
    unsigned short* wob = wts + (size_t)3 * Cz * Cz;
    unsigned short* ry  = xk;   // xk dead after k-GEMM; reuse for r*y

    f2b_k<<<dim3(Cz * Cz / 4 / 256, 4), dim3(256), 0, stream>>>(Wk, Wv, Wr, Wo, wts);

    mix_k<<<dim3(Mz * Cz / 4 / 256), dim3(256), 0, stream>>>(x, mk, mv, mr, xk, xv, xr);

    // fused k/v/r GEMMs: z=0 k->f16, z=1 v->bf16, z=2 r->sigmoid bf16
    gemm_bt<<<dim3(8, 256, 3), dim3(256), 0, stream>>>(
        xk, xv, xr, wkb, wvb, wrb, (void*)kf, (void*)vb, (void*)rb,
        (3) | (1 << 4) | (2 << 8));

    wkv_pass1<<<dim3(Bz * Sz * Cz / 2 / 256), dim3(256), 0, stream>>>(kf, vb, td, SA, SB);
    wkv_pass2<<<dim3(Bz * Cz / 2 / 256), dim3(256), 0, stream>>>(td, SA, SB);
    wkv_pass3<<<dim3(Bz * Sz * Cz / 2 / 256), dim3(256), 0, stream>>>(kf, vb, rb, td, tf,
                                                                      SA, SB, ry);

    // out = (r*y) @ Wo^T, fp32
    gemm_bt<<<dim3(8, 256, 1), dim3(256), 0, stream>>>(
        ry, ry, ry, wob, wob, wob, d_out, d_out, d_out, 0);
}